// Round 3
// baseline (531.981 us; speedup 1.0000x reference)
//
#include <hip/hip_runtime.h>
#include <hip/hip_bf16.h>

// Complex ConvLSTM cell. INPUTS: float32. OUTPUT: float32 (verified R2: bf16
// writes into d_out produced error == max|c_new| leaking into f32 h region).
// Decomposition:
//   Z[m][cin]  : m = b*4096 + y*64 + x  (65536 pixels), cin 0..255 =
//                [xr(0:64) | hr(0:64) | xi(0:64) | hi(0:64)]
//   Wp[n][tap][cin] : n = part*64 + ch, parts {0:yr_i,1:yi_i,2:yr_o,3:yi_o,4:yr_c,5:yi_c}
//                yr -> [Wr ; -Wi],  yi -> [Wi ; Wr]
//   gates[ch_n][m] = implicit GEMM (M=384 ch, N=65536 px, K=9 taps x 256 cin) + bias
//   epilogue: sigmoid/tanh + complex recombination -> h_new, c_new (f32, concat)

typedef __attribute__((ext_vector_type(8))) short short8;   // 8 x bf16 bits
typedef __attribute__((ext_vector_type(4))) float floatx4;

#define MTOT   65536      // 16*64*64 pixels
#define HSIZE  8388608    // 16*128*64*64 (one output tensor, elements)
#define LDSS   72         // padded LDS row stride (bf16 elements): 64 + 8

__device__ __forceinline__ short f2bf(float f) {
  __hip_bfloat16 h = __float2bfloat16(f);
  return *reinterpret_cast<short*>(&h);
}

// ---------------------------------------------------------------- pack Z (f32 -> bf16)
__global__ __launch_bounds__(256) void pack_z_kernel(
    const float* __restrict__ xs, const float* __restrict__ hs,
    short* __restrict__ Z) {
  int g = blockIdx.x * 256 + threadIdx.x;   // 65536 * 32 threads
  int m  = g >> 5;
  int cg = (g & 31) * 8;                    // cin group of 8 (stays in one source block)
  int b  = m >> 12;
  int sp = m & 4095;
  int sel = cg >> 6;                        // 0:x lo  1:h lo  2:x hi  3:h hi
  const float* base = (sel & 1) ? hs : xs;
  int ch0 = (cg & 63) + ((sel & 2) ? 64 : 0);
  short8 v;
#pragma unroll
  for (int j = 0; j < 8; ++j)
    v[j] = f2bf(base[(b * 128 + ch0 + j) * 4096 + sp]);
  *(short8*)(Z + m * 256 + cg) = v;
}

// ---------------------------------------------------------------- pack W + bias (f32 in)
__global__ __launch_bounds__(256) void pack_w_kernel(
    const float* __restrict__ Wr_i, const float* __restrict__ Wi_i,
    const float* __restrict__ Wr_o, const float* __restrict__ Wi_o,
    const float* __restrict__ Wr_c, const float* __restrict__ Wi_c,
    const float* __restrict__ br_i, const float* __restrict__ bi_i,
    const float* __restrict__ br_o, const float* __restrict__ bi_o,
    const float* __restrict__ br_c, const float* __restrict__ bi_c,
    short* __restrict__ Wp, float* __restrict__ bias) {
  int g = blockIdx.x * 256 + threadIdx.x;
  if (g >= 384 * 9 * 256) return;
  int cin = g & 255;
  int tap = (g >> 8) % 9;
  int n   = g / (256 * 9);
  int part = n >> 6, ch = n & 63;
  const float *Wr, *Wi;
  if (part < 2)      { Wr = Wr_i; Wi = Wi_i; }
  else if (part < 4) { Wr = Wr_o; Wi = Wi_o; }
  else               { Wr = Wr_c; Wi = Wi_c; }
  int im = part & 1;          // imaginary output part?
  int ci = cin & 127;
  int second = cin >> 7;      // zi half?
  const float* src = im ? (second ? Wr : Wi) : (second ? Wi : Wr);
  float f = src[(ch * 128 + ci) * 9 + tap];
  if (!im && second) f = -f;  // exact negation in f32
  Wp[(n * 9 + tap) * 256 + cin] = f2bf(f);
  if (g < 384) {
    int p2 = g >> 6, c2 = g & 63;
    const float* bs = (p2 == 0) ? br_i : (p2 == 1) ? bi_i : (p2 == 2) ? br_o
                    : (p2 == 3) ? bi_o : (p2 == 4) ? br_c : bi_c;
    bias[g] = bs[c2];
  }
}

// ---------------------------------------------------------------- implicit GEMM
// block: 64 channels (MFMA-M) x 128 pixels (MFMA-N); 4 waves, each 32ch x 64px
// K-loop: 9 taps x 4 chunks of 64 cin. LDS rows padded to 72 elements.
__global__ __launch_bounds__(256) void conv_gemm(
    const short* __restrict__ Z, const short* __restrict__ Wp,
    const float* __restrict__ bias, __hip_bfloat16* __restrict__ gates) {
  __shared__ short As[64 * LDSS];    // weight tile  [ch][k]
  __shared__ short Bs[128 * LDSS];   // pixel tile   [px][k]

  const int tid = threadIdx.x;
  const int m0 = blockIdx.x * 128;   // pixel tile base (2 image rows, same b)
  const int n0 = blockIdx.y * 64;    // channel tile base
  const int wv = tid >> 6;
  const int lane = tid & 63;
  const int l15 = lane & 15, l4 = lane >> 4;
  const int wch = (wv & 1) * 32;
  const int wpx = (wv >> 1) * 64;

  floatx4 acc[2][4];
#pragma unroll
  for (int i = 0; i < 2; ++i)
#pragma unroll
    for (int j = 0; j < 4; ++j)
#pragma unroll
      for (int r = 0; r < 4; ++r) acc[i][j][r] = 0.f;

  for (int tap = 0; tap < 9; ++tap) {
    const int dy = tap / 3 - 1, dx = tap % 3 - 1;
    for (int c0 = 0; c0 < 256; c0 += 64) {
      // stage A (weights): 64 rows x 64 k, 2 vec8 per thread
#pragma unroll
      for (int it = 0; it < 2; ++it) {
        int idx = tid + it * 256;
        int row = idx >> 3, grp = (idx & 7) * 8;
        short8 v = *(const short8*)(Wp + ((n0 + row) * 9 + tap) * 256 + c0 + grp);
        *(short8*)(As + row * LDSS + grp) = v;
      }
      // stage B (pixels, shifted by tap, zero-padded): 128 rows x 64 k, 4 vec8/thread
#pragma unroll
      for (int it = 0; it < 4; ++it) {
        int idx = tid + it * 256;
        int row = idx >> 3, grp = (idx & 7) * 8;
        int p  = m0 + row;
        int yy = ((p >> 6) & 63) + dy;
        int xx = (p & 63) + dx;
        short8 v;
#pragma unroll
        for (int q = 0; q < 8; ++q) v[q] = 0;
        if ((unsigned)yy < 64u && (unsigned)xx < 64u)
          v = *(const short8*)(Z + (((p >> 12) * 64 + yy) * 64 + xx) * 256 + c0 + grp);
        *(short8*)(Bs + row * LDSS + grp) = v;
      }
      __syncthreads();
#pragma unroll
      for (int kk = 0; kk < 64; kk += 32) {
        const int ko = kk + l4 * 8;
        short8 a0 = *(const short8*)(As + (wch +      l15) * LDSS + ko);
        short8 a1 = *(const short8*)(As + (wch + 16 + l15) * LDSS + ko);
        short8 b0 = *(const short8*)(Bs + (wpx +      l15) * LDSS + ko);
        short8 b1 = *(const short8*)(Bs + (wpx + 16 + l15) * LDSS + ko);
        short8 b2 = *(const short8*)(Bs + (wpx + 32 + l15) * LDSS + ko);
        short8 b3 = *(const short8*)(Bs + (wpx + 48 + l15) * LDSS + ko);
        acc[0][0] = __builtin_amdgcn_mfma_f32_16x16x32_bf16(a0, b0, acc[0][0], 0, 0, 0);
        acc[0][1] = __builtin_amdgcn_mfma_f32_16x16x32_bf16(a0, b1, acc[0][1], 0, 0, 0);
        acc[0][2] = __builtin_amdgcn_mfma_f32_16x16x32_bf16(a0, b2, acc[0][2], 0, 0, 0);
        acc[0][3] = __builtin_amdgcn_mfma_f32_16x16x32_bf16(a0, b3, acc[0][3], 0, 0, 0);
        acc[1][0] = __builtin_amdgcn_mfma_f32_16x16x32_bf16(a1, b0, acc[1][0], 0, 0, 0);
        acc[1][1] = __builtin_amdgcn_mfma_f32_16x16x32_bf16(a1, b1, acc[1][1], 0, 0, 0);
        acc[1][2] = __builtin_amdgcn_mfma_f32_16x16x32_bf16(a1, b2, acc[1][2], 0, 0, 0);
        acc[1][3] = __builtin_amdgcn_mfma_f32_16x16x32_bf16(a1, b3, acc[1][3], 0, 0, 0);
      }
      __syncthreads();
    }
  }
  // store: D reg r, lane: ch = l4*4 + r, px = l15 (per 16x16 subtile)
#pragma unroll
  for (int i = 0; i < 2; ++i)
#pragma unroll
    for (int j = 0; j < 4; ++j) {
#pragma unroll
      for (int r = 0; r < 4; ++r) {
        int ch = n0 + wch + i * 16 + l4 * 4 + r;
        int px = m0 + wpx + j * 16 + l15;
        gates[ch * MTOT + px] = __float2bfloat16(acc[i][j][r] + bias[ch]);
      }
    }
}

// ---------------------------------------------------------------- epilogue (f32 out)
__device__ __forceinline__ float fsig(float v) { return 1.f / (1.f + __expf(-v)); }
__device__ __forceinline__ float ftanh(float v) {
  float e = __expf(2.f * v);
  return 1.f - 2.f / (e + 1.f);
}

__global__ __launch_bounds__(256) void epilogue_kernel(
    const __hip_bfloat16* __restrict__ gates,
    const float* __restrict__ x,
    const float* __restrict__ c_prev,
    float* __restrict__ out) {
  int g = blockIdx.x * 256 + threadIdx.x;   // 64 ch * 65536 px
  int m  = g & (MTOT - 1);
  int ch = g >> 16;
  int b = m >> 12, sp = m & 4095;
  float yri = __bfloat162float(gates[(0 * 64 + ch) * MTOT + m]);
  float yii = __bfloat162float(gates[(1 * 64 + ch) * MTOT + m]);
  float yro = __bfloat162float(gates[(2 * 64 + ch) * MTOT + m]);
  float yio = __bfloat162float(gates[(3 * 64 + ch) * MTOT + m]);
  float yrc = __bfloat162float(gates[(4 * 64 + ch) * MTOT + m]);
  float yic = __bfloat162float(gates[(5 * 64 + ch) * MTOT + m]);
  float i_r = fsig(yri), i_i = fsig(yii);
  float o_r = fsig(yro), o_i = fsig(yio);
  float ct_r = ftanh(yrc), ct_i = ftanh(yic);
  int base = (b * 128 + ch) * 4096 + sp;
  float xr = x[base];
  float xi = x[base + 64 * 4096];
  float cr = c_prev[base];
  float ci = c_prev[base + 64 * 4096];
  float cnr = xr * cr - xi * ci + i_r * ct_r - i_i * ct_i;
  float cni = xr * ci + xi * cr + i_r * ct_i + i_i * ct_r;
  float tr = ftanh(cnr), ti = ftanh(cni);
  out[base]                     = o_r * tr - o_i * ti;
  out[base + 64 * 4096]         = o_r * ti + o_i * tr;
  out[HSIZE + base]             = cnr;
  out[HSIZE + base + 64 * 4096] = cni;
}

// ---------------------------------------------------------------- launch
extern "C" void kernel_launch(void* const* d_in, const int* in_sizes, int n_in,
                              void* d_out, int out_size, void* d_ws, size_t ws_size,
                              hipStream_t stream) {
  // inputs: 0 x, 1 h_prev, 2 c_prev,
  //         3 Wr_i, 4 Wi_i, 5 br_i, 6 bi_i,  7 Wr_f, 8 Wi_f, 9 br_f, 10 bi_f (unused),
  //        11 Wr_o,12 Wi_o,13 br_o,14 bi_o, 15 Wr_c,16 Wi_c,17 br_c,18 bi_c
  const float* x  = (const float*)d_in[0];
  const float* h  = (const float*)d_in[1];

  char* ws = (char*)d_ws;
  short* Z    = (short*)ws;                         // 33,554,432 B
  short* Wp   = (short*)(ws + 33554432);            //  1,769,472 B
  float* bias = (float*)(ws + 35323904);            //      1,536 B
  __hip_bfloat16* gates = (__hip_bfloat16*)(ws + 35325440); // 50,331,648 B
  // total ws use: ~81.7 MiB

  pack_z_kernel<<<8192, 256, 0, stream>>>(x, h, Z);
  pack_w_kernel<<<3456, 256, 0, stream>>>(
      (const float*)d_in[3], (const float*)d_in[4],
      (const float*)d_in[11], (const float*)d_in[12],
      (const float*)d_in[15], (const float*)d_in[16],
      (const float*)d_in[5], (const float*)d_in[6],
      (const float*)d_in[13], (const float*)d_in[14],
      (const float*)d_in[17], (const float*)d_in[18],
      Wp, bias);
  conv_gemm<<<dim3(512, 6), 256, 0, stream>>>(Z, Wp, bias, gates);
  epilogue_kernel<<<16384, 256, 0, stream>>>(
      gates, (const float*)d_in[0], (const float*)d_in[2],
      (float*)d_out);
}

// Round 4
// 313.732 us; speedup vs baseline: 1.6957x; 1.6957x over previous
//
#include <hip/hip_runtime.h>
#include <hip/hip_bf16.h>

// Complex ConvLSTM cell. Inputs f32, output f32 (verified R3, absmax 0.0625).
//   Zp: halo-padded packed activations, [b][y' 0..65][x' 0..65][cin 0..255] bf16
//       cin = [x lo | h lo | x hi | h hi]; halo = zeros.
//   Wp[n][tap][cin]: n = part*64+ch, parts {yr_i,yi_i,yr_o,yi_o,yr_c,yi_c};
//       yr -> [Wr ; -Wi], yi -> [Wi ; Wr].
//   conv_gemm: 128ch x 128px block tile, global_load_lds(16B) staging,
//       XOR-swizzled LDS k-groups, dy-grouped taps (B staged once per 3 dx).
//   epilogue: gate math -> h_new, c_new (f32).

typedef __attribute__((ext_vector_type(8))) short short8;
typedef __attribute__((ext_vector_type(4))) float floatx4;
typedef __attribute__((ext_vector_type(4))) float float4v;

#define MTOT   65536
#define HSIZE  8388608
#define ZP_ELEMS (16 * 66 * 66 * 256)          // 17,842,176 shorts

__device__ __forceinline__ short f2bf(float f) {
  __hip_bfloat16 h = __float2bfloat16(f);
  return *reinterpret_cast<short*>(&h);
}

__device__ __forceinline__ void gload16(const short* g, void* lds) {
  __builtin_amdgcn_global_load_lds(
      (__attribute__((address_space(1))) void*)(g),
      (__attribute__((address_space(3))) void*)(lds), 16, 0, 0);
}

// ---------------------------------------------------------------- halo zero
__global__ __launch_bounds__(256) void halo_zero_kernel(short* __restrict__ Zp) {
  int t = blockIdx.x * 256 + threadIdx.x;     // 520*256 = 133,120 = 4160 px * 32
  int s   = t & 31;
  int pix = t >> 5;                           // 0..4159
  int b = pix / 260;
  int r = pix - b * 260;
  int yp, xp;
  if (r < 66)       { yp = 0;               xp = r; }
  else if (r < 132) { yp = 65;              xp = r - 66; }
  else { int r2 = r - 132; yp = 1 + (r2 >> 1); xp = (r2 & 1) * 65; }
  short8 z;
#pragma unroll
  for (int q = 0; q < 8; ++q) z[q] = 0;
  *(short8*)(Zp + (((b * 66 + yp) * 66 + xp) * 256 + s * 8)) = z;
}

// ---------------------------------------------------------------- pack Z (tiled transpose)
// block: one (b, srcSel, half, y) -> 64ch x 64x tile
__global__ __launch_bounds__(256) void pack_z_kernel(
    const float* __restrict__ xs, const float* __restrict__ hs,
    short* __restrict__ Zp) {
  __shared__ short tile[64 * 72];             // [xr][ch], stride 72 (16B-aligned rows)
  int bid = blockIdx.x;
  int y      = bid & 63;
  int half   = (bid >> 6) & 1;
  int srcSel = (bid >> 7) & 1;
  int b      = bid >> 8;
  const float* src = srcSel ? hs : xs;
  int chBase  = half * 64;
  int cinBase = half * 128 + srcSel * 64;
  int t = threadIdx.x;
  int x4 = t & 15, chq = t >> 4;              // 16 ch per pass
#pragma unroll
  for (int p = 0; p < 4; ++p) {
    int ch = p * 16 + chq;
    float4v f = *(const float4v*)(src + (size_t)(b * 128 + chBase + ch) * 4096 + y * 64 + x4 * 4);
#pragma unroll
    for (int e = 0; e < 4; ++e)
      tile[(x4 * 4 + e) * 72 + ch] = f2bf(f[e]);
  }
  __syncthreads();
  int x = t >> 2, seg = t & 3;
  short8 v0 = *(const short8*)(tile + x * 72 + seg * 16);
  short8 v1 = *(const short8*)(tile + x * 72 + seg * 16 + 8);
  size_t outp = ((size_t)(b * 66 + y + 1) * 66 + x + 1) * 256 + cinBase + seg * 16;
  *(short8*)(Zp + outp)     = v0;
  *(short8*)(Zp + outp + 8) = v1;
}

// ---------------------------------------------------------------- pack W + bias
__global__ __launch_bounds__(256) void pack_w_kernel(
    const float* __restrict__ Wr_i, const float* __restrict__ Wi_i,
    const float* __restrict__ Wr_o, const float* __restrict__ Wi_o,
    const float* __restrict__ Wr_c, const float* __restrict__ Wi_c,
    const float* __restrict__ br_i, const float* __restrict__ bi_i,
    const float* __restrict__ br_o, const float* __restrict__ bi_o,
    const float* __restrict__ br_c, const float* __restrict__ bi_c,
    short* __restrict__ Wp, float* __restrict__ bias) {
  int g = blockIdx.x * 256 + threadIdx.x;
  if (g >= 384 * 9 * 256) return;
  int cin = g & 255;
  int tap = (g >> 8) % 9;
  int n   = g / (256 * 9);
  int part = n >> 6, ch = n & 63;
  const float *Wr, *Wi;
  if (part < 2)      { Wr = Wr_i; Wi = Wi_i; }
  else if (part < 4) { Wr = Wr_o; Wi = Wi_o; }
  else               { Wr = Wr_c; Wi = Wi_c; }
  int im = part & 1;
  int ci = cin & 127;
  int second = cin >> 7;
  const float* src = im ? (second ? Wr : Wi) : (second ? Wi : Wr);
  float f = src[(ch * 128 + ci) * 9 + tap];
  if (!im && second) f = -f;
  Wp[(n * 9 + tap) * 256 + cin] = f2bf(f);
  if (g < 384) {
    int p2 = g >> 6, c2 = g & 63;
    const float* bs = (p2 == 0) ? br_i : (p2 == 1) ? bi_i : (p2 == 2) ? br_o
                    : (p2 == 3) ? bi_o : (p2 == 4) ? br_c : bi_c;
    bias[g] = bs[c2];
  }
}

// ---------------------------------------------------------------- implicit GEMM
// 128ch x 128px tile, 4 waves (each 64x64), K = 9 taps x 256 cin.
// LDS: As[row 0..127][slot 0..7] 16B slots, slot p holds logical k-group p^(row&7).
//      Bs[r2 0..1][col 0..65][slot 0..7], slot p holds logical group p^(col&7).
// Staged via global_load_lds (dest = wave base + lane*16, lane-contiguous).
__global__ __launch_bounds__(256, 3) void conv_gemm(
    const short* __restrict__ Z, const short* __restrict__ Wp,
    const float* __restrict__ bias, __hip_bfloat16* __restrict__ gates) {
  __shared__ short8 As[1024];   // 16 KiB
  __shared__ short8 Bs[1056];   // 16.5 KiB

  const int tid = threadIdx.x;
  const int wv = tid >> 6, lane = tid & 63;
  const int l15 = lane & 15, l4 = lane >> 4;
  const int m0 = blockIdx.x * 128;
  const int n0 = blockIdx.y * 128;
  const int b  = m0 >> 12;
  const int y0 = (m0 >> 6) & 63;    // even
  const int wch = (wv & 1) * 64;    // wave channel offset
  const int r2w = wv >> 1;          // wave pixel-row (0/1) within tile

  floatx4 acc[4][4];
#pragma unroll
  for (int i = 0; i < 4; ++i)
#pragma unroll
    for (int j = 0; j < 4; ++j)
#pragma unroll
      for (int r = 0; r < 4; ++r) acc[i][j][r] = 0.f;

  for (int dy = -1; dy <= 1; ++dy) {
    for (int c0 = 0; c0 < 256; c0 += 64) {
      // ---- stage B: rows y0+dy, y0+1+dy; cols -1..64 (halo-padded Z) ----
#pragma unroll
      for (int it = 0; it < 5; ++it) {
        int idx = tid + it * 256;
        if (idx < 1056) {
          int r2  = (idx >= 528) ? 1 : 0;
          int rem = idx - r2 * 528;
          int col = rem >> 3, p = rem & 7;
          int g   = p ^ (col & 7);
          int ygl = b * 66 + y0 + dy + 1 + r2;
          gload16(Z + ((size_t)(ygl * 66 + col) * 256 + c0 + g * 8),
                  (void*)(Bs + (it * 256 + wv * 64)));
        }
      }
      for (int dx = -1; dx <= 1; ++dx) {
        int tap = (dy + 1) * 3 + (dx + 1);
        // ---- stage A: 128 rows x 64 k ----
#pragma unroll
        for (int it = 0; it < 4; ++it) {
          int idx = tid + it * 256;
          int row = idx >> 3, p = idx & 7;
          int g   = p ^ (row & 7);
          gload16(Wp + ((size_t)((n0 + row) * 9 + tap) * 256 + c0 + g * 8),
                  (void*)(As + (it * 256 + wv * 64)));
        }
        __syncthreads();   // drains vmcnt(0): A + (first iter) B visible
#pragma unroll
        for (int kk = 0; kk < 2; ++kk) {
          int kg = kk * 4 + l4;
          short8 a[4], bf[4];
#pragma unroll
          for (int i = 0; i < 4; ++i) {
            int row = wch + i * 16 + l15;
            a[i] = As[row * 8 + (kg ^ (row & 7))];
          }
#pragma unroll
          for (int j = 0; j < 4; ++j) {
            int col = j * 16 + l15 + dx + 1;
            bf[j] = Bs[r2w * 528 + col * 8 + (kg ^ (col & 7))];
          }
#pragma unroll
          for (int i = 0; i < 4; ++i)
#pragma unroll
            for (int j = 0; j < 4; ++j)
              acc[i][j] = __builtin_amdgcn_mfma_f32_16x16x32_bf16(a[i], bf[j], acc[i][j], 0, 0, 0);
        }
        __syncthreads();   // As (and Bs at dx==1) free for restage
      }
    }
  }
#pragma unroll
  for (int i = 0; i < 4; ++i)
#pragma unroll
    for (int j = 0; j < 4; ++j)
#pragma unroll
      for (int r = 0; r < 4; ++r) {
        int ch = n0 + wch + i * 16 + l4 * 4 + r;
        int px = m0 + r2w * 64 + j * 16 + l15;
        gates[(size_t)ch * MTOT + px] = __float2bfloat16(acc[i][j][r] + bias[ch]);
      }
}

// ---------------------------------------------------------------- epilogue (f32 out)
__device__ __forceinline__ float fsig(float v) { return 1.f / (1.f + __expf(-v)); }
__device__ __forceinline__ float ftanh(float v) {
  float e = __expf(2.f * v);
  return 1.f - 2.f / (e + 1.f);
}

__global__ __launch_bounds__(256) void epilogue_kernel(
    const __hip_bfloat16* __restrict__ gates,
    const float* __restrict__ x,
    const float* __restrict__ c_prev,
    float* __restrict__ out) {
  int g = blockIdx.x * 256 + threadIdx.x;
  int m  = g & (MTOT - 1);
  int ch = g >> 16;
  int b = m >> 12, sp = m & 4095;
  float yri = __bfloat162float(gates[(size_t)(0 * 64 + ch) * MTOT + m]);
  float yii = __bfloat162float(gates[(size_t)(1 * 64 + ch) * MTOT + m]);
  float yro = __bfloat162float(gates[(size_t)(2 * 64 + ch) * MTOT + m]);
  float yio = __bfloat162float(gates[(size_t)(3 * 64 + ch) * MTOT + m]);
  float yrc = __bfloat162float(gates[(size_t)(4 * 64 + ch) * MTOT + m]);
  float yic = __bfloat162float(gates[(size_t)(5 * 64 + ch) * MTOT + m]);
  float i_r = fsig(yri), i_i = fsig(yii);
  float o_r = fsig(yro), o_i = fsig(yio);
  float ct_r = ftanh(yrc), ct_i = ftanh(yic);
  int base = (b * 128 + ch) * 4096 + sp;
  float xr = x[base];
  float xi = x[base + 64 * 4096];
  float cr = c_prev[base];
  float ci = c_prev[base + 64 * 4096];
  float cnr = xr * cr - xi * ci + i_r * ct_r - i_i * ct_i;
  float cni = xr * ci + xi * cr + i_r * ct_i + i_i * ct_r;
  float tr = ftanh(cnr), ti = ftanh(cni);
  out[base]                     = o_r * tr - o_i * ti;
  out[base + 64 * 4096]         = o_r * ti + o_i * tr;
  out[HSIZE + base]             = cnr;
  out[HSIZE + base + 64 * 4096] = cni;
}

// ---------------------------------------------------------------- launch
extern "C" void kernel_launch(void* const* d_in, const int* in_sizes, int n_in,
                              void* d_out, int out_size, void* d_ws, size_t ws_size,
                              hipStream_t stream) {
  // inputs: 0 x, 1 h_prev, 2 c_prev,
  //         3 Wr_i, 4 Wi_i, 5 br_i, 6 bi_i,  7..10 f-gate (unused),
  //        11 Wr_o,12 Wi_o,13 br_o,14 bi_o, 15 Wr_c,16 Wi_c,17 br_c,18 bi_c
  const float* x = (const float*)d_in[0];
  const float* h = (const float*)d_in[1];

  char* ws = (char*)d_ws;
  short* Zp   = (short*)ws;                          // 35,684,352 B
  short* Wp   = (short*)(ws + 35684352);             //  1,769,472 B
  float* bias = (float*)(ws + 37453824);             //      1,536 B
  __hip_bfloat16* gates = (__hip_bfloat16*)(ws + 37455360); // 50,331,648 B
  // total ~87.8 MiB

  halo_zero_kernel<<<520, 256, 0, stream>>>(Zp);
  pack_z_kernel<<<4096, 256, 0, stream>>>(x, h, Zp);
  pack_w_kernel<<<3456, 256, 0, stream>>>(
      (const float*)d_in[3], (const float*)d_in[4],
      (const float*)d_in[11], (const float*)d_in[12],
      (const float*)d_in[15], (const float*)d_in[16],
      (const float*)d_in[5], (const float*)d_in[6],
      (const float*)d_in[13], (const float*)d_in[14],
      (const float*)d_in[17], (const float*)d_in[18],
      Wp, bias);
  conv_gemm<<<dim3(512, 3), 256, 0, stream>>>(Zp, Wp, bias, gates);
  epilogue_kernel<<<16384, 256, 0, stream>>>(
      gates, (const float*)d_in[0], (const float*)d_in[2],
      (float*)d_out);
}